// Round 3
// baseline (165.401 us; speedup 1.0000x reference)
//
#include <hip/hip_runtime.h>
#include <math.h>

// Problem constants
#define B_   64
#define T_   512
#define D_   96
#define TY_  512
#define H_   4
#define DK_  32
#define E_   128
#define P_   2
#define L_   64
#define HID_ 128

// Workspace layout (float offsets)
#define WS_PN    2048      // 64b*8c*8hp*96f = 393216 : partial numerators
#define WS_PD    395264    // 393216 : partial denominators
#define WS_AB    788480    // 64*2*128 = 16384 : decoder a0/a1

// ---------------------------------------------------------------------------
// Kernel SP (fused prep + scores + exp + pool): grid (8 t-chunks, 64 b), 256 thr.
// Prologue (redundant per block, ~250 fma/thread, k_w/q_w hit L2):
//   qm[p,e'] = query[p,:] @ q_w + q_b
//   w2q[e,hp] = sum_dk k_w[e,h*32+dk]*qm[p,h*32+dk]/sqrt(32);  bq likewise
// Phase A: w[t,hp] = exp(emb(t) . w2q[:,hp] + bq[hp])   (no max-sub: |s|<~20)
// Phase B: num[hp,f] += w*M*X ; den[hp,f] += w*M  over the 64-t chunk
// ---------------------------------------------------------------------------
__global__ __launch_bounds__(256) void kspool(
    const float* __restrict__ tsteps, const float* __restrict__ te_w,
    const float* __restrict__ te_b,   const float* __restrict__ X,
    const float* __restrict__ M,      const float* __restrict__ query,
    const float* __restrict__ q_w,    const float* __restrict__ q_b,
    const float* __restrict__ k_w,    const float* __restrict__ k_b,
    float* __restrict__ ws)
{
    const int c = blockIdx.x, b = blockIdx.y, tid = threadIdx.x;
    __shared__ float qm[P_ * E_];
    __shared__ float w2q_s[E_ * 8];
    __shared__ float tw_s[E_], tb_s[E_], bq_s[8];
    __shared__ float w_s[64 * 8];
    __shared__ float red[96 * 17];  // stride 17: no bank conflicts

    // ---- Prologue: fused q/k weights ----
    {
        int p = tid >> 7, ep = tid & 127;
        float acc = q_b[ep];
        #pragma unroll 4
        for (int e = 0; e < E_; ++e)
            acc += query[p * E_ + e] * q_w[e * E_ + ep];
        qm[p * E_ + ep] = acc;
    }
    if (tid < E_) { tw_s[tid] = te_w[tid]; tb_s[tid] = te_b[tid]; }
    __syncthreads();
    const float rs = 0.17677669529663687f;  // 1/sqrt(32)
    #pragma unroll
    for (int i = 0; i < 4; ++i) {
        int idx = tid + i * 256;
        int e = idx >> 3, hp = idx & 7, h = hp >> 1, p = hp & 1;
        float acc = 0.f;
        #pragma unroll
        for (int dk = 0; dk < DK_; ++dk)
            acc += k_w[e * E_ + h * DK_ + dk] * qm[p * E_ + h * DK_ + dk];
        w2q_s[idx] = acc * rs;
    }
    if (tid < 8) {
        int hp = tid, h = hp >> 1, p = hp & 1;
        float acc = 0.f;
        #pragma unroll
        for (int dk = 0; dk < DK_; ++dk)
            acc += k_b[h * DK_ + dk] * qm[p * E_ + h * DK_ + dk];
        bq_s[hp] = acc * rs;
    }
    __syncthreads();

    // ---- Phase A: thread = (t in chunk, hp-pair) ----
    {
        const int t = tid & 63, hpg = tid >> 6, hp0 = hpg * 2;
        const float tv = tsteps[b * T_ + c * 64 + t];
        float a0 = 0.f, a1 = 0.f;
        #pragma unroll 4
        for (int e = 0; e < E_; ++e) {
            float v = tv * tw_s[e] + tb_s[e];
            if ((e & 3) == 0) v = __sinf(v);
            float2 w = *(const float2*)&w2q_s[e * 8 + hp0];
            a0 += v * w.x;
            a1 += v * w.y;
        }
        w_s[t * 8 + hp0]     = __expf(a0 + bq_s[hp0]);
        w_s[t * 8 + hp0 + 1] = __expf(a1 + bq_s[hp0 + 1]);
    }
    __syncthreads();

    // ---- Phase B: 2 t-slices x 128 fid (96 active) ----
    const int fid = tid & 127, slice = tid >> 7;
    float num[8] = {0.f, 0.f, 0.f, 0.f, 0.f, 0.f, 0.f, 0.f};
    float den[8] = {0.f, 0.f, 0.f, 0.f, 0.f, 0.f, 0.f, 0.f};
    if (fid < 96) {
        #pragma unroll 4
        for (int i = 0; i < 32; ++i) {
            int tl = slice + 2 * i;
            size_t base = ((size_t)(b * T_ + c * 64 + tl)) * D_ + fid;
            float m = M[base], x = X[base];
            float mx = m * x;
            const float* wr = w_s + tl * 8;
            #pragma unroll
            for (int hp = 0; hp < 8; ++hp) {
                num[hp] += wr[hp] * mx;
                den[hp] += wr[hp] * m;
            }
        }
    }
    __syncthreads();
    if (slice == 1 && fid < 96) {
        #pragma unroll
        for (int hp = 0; hp < 8; ++hp) {
            red[fid * 17 + hp]     = num[hp];
            red[fid * 17 + 8 + hp] = den[hp];
        }
    }
    __syncthreads();
    if (slice == 0 && fid < 96) {
        float* pN = ws + WS_PN + ((size_t)((b * 8 + c) * 8)) * 96;
        float* pD = ws + WS_PD + ((size_t)((b * 8 + c) * 8)) * 96;
        #pragma unroll
        for (int hp = 0; hp < 8; ++hp) {
            pN[hp * 96 + fid] = num[hp] + red[fid * 17 + hp];
            pD[hp * 96 + fid] = den[hp] + red[fid * 17 + 8 + hp];
        }
    }
}

// ---------------------------------------------------------------------------
// Kernel A2: reduce partials -> xa -> coeffs -> decoder a0/a1.
// 64 blocks x 512 threads; full (h,p,l) split of the coeff GEMV, 4-way l-split
// of the a0/a1 GEMV, ob2 (constant half of xa) folded in per-block.
// ---------------------------------------------------------------------------
__global__ __launch_bounds__(512) void kcoef(
    const float* __restrict__ ow, const float* __restrict__ w1,
    const float* __restrict__ b1, const float* __restrict__ ob,
    float* __restrict__ ws)
{
    const int b = blockIdx.x, tid = threadIdx.x;
    __shared__ float xa_s[8 * 96];
    __shared__ float obp[8][64];        // ob2 partials (8 slices)
    __shared__ float cfp[4][2][64];     // coeff partials per h
    __shared__ float cf_s[2][64];
    __shared__ float abp[4][2][128];    // a0/a1 partials (4 l-slices)

    // phase 0a: reduce pool partials -> xa
    for (int flat = tid; flat < 8 * 96; flat += 512) {
        int hp = flat / 96, f = flat - hp * 96;
        float n = 0.f, d = 0.f;
        #pragma unroll
        for (int c = 0; c < 8; ++c) {
            n += ws[WS_PN + ((size_t)((b * 8 + c) * 8 + hp)) * 96 + f];
            d += ws[WS_PD + ((size_t)((b * 8 + c) * 8 + hp)) * 96 + f];
        }
        xa_s[flat] = n / d;
    }
    // phase 0b: ob2 partials (xa second half == 1 -> folds ow rows into bias)
    {
        int g = tid >> 6, l = tid & 63;   // g: 8 slices of the 384 (h,j) pairs
        float acc = 0.f;
        #pragma unroll 4
        for (int k = 0; k < 48; ++k) {
            int hj = g * 48 + k, h = hj / 96, j = hj - h * 96;
            acc += ow[(size_t)(h * 2 * D_ + D_ + j) * L_ + l];
        }
        obp[g][l] = acc;
    }
    __syncthreads();

    // phase 1: coeff GEMV, thread = (h, p, l)
    {
        int h = tid >> 7, p = (tid >> 6) & 1, l = tid & 63;
        const float* xr = xa_s + (h * 2 + p) * 96;
        const float* owr = ow + (size_t)(h * 2 * D_) * L_ + l;
        float acc = 0.f;
        #pragma unroll 4
        for (int f = 0; f < 96; ++f)
            acc += xr[f] * owr[(size_t)f * L_];
        cfp[h][p][l] = acc;
    }
    __syncthreads();

    // phase 2: combine coeff partials + bias
    if (tid < 128) {
        int p = tid >> 6, l = tid & 63;
        float v = cfp[0][p][l] + cfp[1][p][l] + cfp[2][p][l] + cfp[3][p][l] + ob[l];
        #pragma unroll
        for (int g = 0; g < 8; ++g) v += obp[g][l];
        cf_s[p][l] = v;
    }
    __syncthreads();

    // phase 3: a0/a1 GEMV, thread = (l-slice, j)
    {
        int s = tid >> 7, j = tid & 127;
        float a0 = 0.f, a1 = 0.f;
        #pragma unroll
        for (int li = 0; li < 16; ++li) {
            int l = s * 16 + li;
            float wv = w1[l * HID_ + j];
            a0 += cf_s[0][l] * wv;
            a1 += cf_s[1][l] * wv;
        }
        abp[s][0][j] = a0;
        abp[s][1][j] = a1;
    }
    __syncthreads();

    // phase 4: combine + write a0/a1
    if (tid < 256) {
        int q = tid >> 7, j = tid & 127;
        float v = abp[0][q][j] + abp[1][q][j] + abp[2][q][j] + abp[3][q][j];
        if (q == 0) v += b1[j];
        ws[WS_AB + b * 256 + q * 128 + j] = v;
    }
}

// ---------------------------------------------------------------------------
// Kernel D: decoder. Block = 64 positions (one b), 256 threads.
//   h[j,pos] = relu(a0[j] + y[pos]*a1[j])   staged in LDS (32 KB)
//   out[pos,d] = sum_j h[j,pos]*w2[j,d] + b2[d]   (4 pos x 6 d per thread)
// ---------------------------------------------------------------------------
__global__ __launch_bounds__(256) void kdec(
    const float* __restrict__ yts, const float* __restrict__ w2,
    const float* __restrict__ b2,  const float* __restrict__ ws,
    float* __restrict__ out)
{
    __shared__ float h_s[HID_ * 64];
    __shared__ float y_s[64];
    __shared__ float a0_s[HID_], a1_s[HID_];
    const int tid = threadIdx.x;
    const int posb = blockIdx.x * 64;   // flat position base (b*512 + ty0)
    const int b = posb >> 9;

    if (tid < 64) y_s[tid] = yts[posb + tid];
    if (tid >= 64 && tid < 192) {
        int j = tid - 64;
        a0_s[j] = ws[WS_AB + b * 256 + j];
        a1_s[j] = ws[WS_AB + b * 256 + 128 + j];
    }
    __syncthreads();

    #pragma unroll 4
    for (int r = 0; r < 32; ++r) {
        int flat = r * 256 + tid;       // = j*64 + pos
        int j = flat >> 6, pos = flat & 63;
        h_s[flat] = fmaxf(0.f, a0_s[j] + y_s[pos] * a1_s[j]);
    }
    __syncthreads();

    const int pg = tid >> 4, dg = tid & 15;
    const int p0 = pg * 4, d0 = dg * 6;
    float acc[4][6];
    #pragma unroll
    for (int pp = 0; pp < 4; ++pp)
        #pragma unroll
        for (int dd = 0; dd < 6; ++dd) acc[pp][dd] = 0.f;

    #pragma unroll 2
    for (int j = 0; j < HID_; ++j) {
        float4 h4 = *(const float4*)&h_s[j * 64 + p0];
        const float* wr = w2 + j * D_ + d0;
        float wv[6];
        #pragma unroll
        for (int dd = 0; dd < 6; ++dd) wv[dd] = wr[dd];
        const float hv[4] = {h4.x, h4.y, h4.z, h4.w};
        #pragma unroll
        for (int pp = 0; pp < 4; ++pp)
            #pragma unroll
            for (int dd = 0; dd < 6; ++dd)
                acc[pp][dd] += hv[pp] * wv[dd];
    }

    float bv[6];
    #pragma unroll
    for (int dd = 0; dd < 6; ++dd) bv[dd] = b2[d0 + dd];
    #pragma unroll
    for (int pp = 0; pp < 4; ++pp) {
        size_t ob = ((size_t)(posb + p0 + pp)) * D_ + d0;
        #pragma unroll
        for (int dd = 0; dd < 6; ++dd) out[ob + dd] = acc[pp][dd] + bv[dd];
    }
}

// ---------------------------------------------------------------------------
extern "C" void kernel_launch(void* const* d_in, const int* in_sizes, int n_in,
                              void* d_out, int out_size, void* d_ws, size_t ws_size,
                              hipStream_t stream)
{
    const float* timesteps = (const float*)d_in[0];
    const float* X         = (const float*)d_in[1];
    const float* M         = (const float*)d_in[2];
    const float* yts       = (const float*)d_in[3];
    const float* te_w      = (const float*)d_in[4];
    const float* te_b      = (const float*)d_in[5];
    const float* query     = (const float*)d_in[6];
    const float* q_w       = (const float*)d_in[7];
    const float* q_b       = (const float*)d_in[8];
    const float* k_w       = (const float*)d_in[9];
    const float* k_b       = (const float*)d_in[10];
    const float* ow        = (const float*)d_in[11];
    const float* ob        = (const float*)d_in[12];
    const float* w1        = (const float*)d_in[13];
    const float* b1        = (const float*)d_in[14];
    const float* w2        = (const float*)d_in[15];
    const float* b2        = (const float*)d_in[16];
    float* out = (float*)d_out;
    float* ws  = (float*)d_ws;

    kspool<<<dim3(8, B_), 256, 0, stream>>>(timesteps, te_w, te_b, X, M,
                                            query, q_w, q_b, k_w, k_b, ws);
    kcoef<<<B_, 512, 0, stream>>>(ow, w1, b1, ob, ws);
    kdec<<<(B_ * TY_) / 64, 256, 0, stream>>>(yts, w2, b2, ws, out);
}